// Round 7
// baseline (10823.753 us; speedup 1.0000x reference)
//
#include <hip/hip_runtime.h>
#include <stdint.h>

#define HDIM 256
#define SEQ  784
#define NB   256
#define NCLS 10
#define NTHR 512
#define LQ   19              // F/O weight quads per thread in LDS (155,648 B)
#define AQ2  13              // F/O weight quads per thread in arch VGPRs (52 regs)
#define FOQ  32              // total F/O quads per thread (128 k-cols x 2 gates)

typedef _Float16 half2_t __attribute__((ext_vector_type(2)));
typedef _Float16 half8_t __attribute__((ext_vector_type(8)));
typedef float    f32x4_t __attribute__((ext_vector_type(4)));

__device__ __forceinline__ half2_t u2h(uint32_t u) {
    union { uint32_t u; half2_t h; } v; v.u = u; return v.h;
}
__device__ __forceinline__ uint32_t pkf16(float a, float b) {
    union { half2_t h; uint32_t u; } v;
    v.h.x = (_Float16)a; v.h.y = (_Float16)b; return v.u;
}
__device__ __forceinline__ half8_t u4h8(uint4 u) {
    union { uint4 u; half8_t h; } v; v.u = u; return v.h;
}

#if __has_builtin(__builtin_amdgcn_fdot2)
__device__ __forceinline__ float dot2(uint32_t h, uint32_t w, float acc) {
    return __builtin_amdgcn_fdot2(u2h(h), u2h(w), acc, false);
}
#else
__device__ __forceinline__ float dot2(uint32_t h, uint32_t w, float acc) {
    half2_t hv = u2h(h), wv = u2h(w);
    acc = fmaf((float)hv.x, (float)wv.x, acc);
    return fmaf((float)hv.y, (float)wv.y, acc);
}
#endif

#if __has_builtin(__builtin_amdgcn_rcpf)
__device__ __forceinline__ float fast_rcp(float x) { return __builtin_amdgcn_rcpf(x); }
#else
__device__ __forceinline__ float fast_rcp(float x) { return 1.f / x; }
#endif

__device__ __forceinline__ float sigmoid_f(float x) {
    return fast_rcp(1.f + __expf(-x));
}
__device__ __forceinline__ float tanh_f(float x) {
    return fmaf(2.f, fast_rcp(1.f + __expf(-2.f * x)), -1.f);
}

// F/O weights: WP[q*NTHR + t], t=(r<<1)|kh, quad q covers k0 = kh*128 + 4q:
// {F(k0,k0+1), F(k0+2,k0+3), O(k0,k0+1), O(k0+2,k0+3)} as f16 pairs.
__global__ __launch_bounds__(NTHR) void pack_wfo(
    const float* __restrict__ Wf, const float* __restrict__ Wo,
    uint4* __restrict__ WP)
{
    const int q = blockIdx.x;          // 0..31
    const int t = threadIdx.x;         // 0..511
    const int r = t >> 1, kh = t & 1;
    const int k0 = kh * 128 + 4 * q;
    const float* f = Wf + r * HDIM + k0;
    const float* o = Wo + r * HDIM + k0;
    uint4 v;
    v.x = pkf16(f[0], f[1]);
    v.y = pkf16(f[2], f[3]);
    v.z = pkf16(o[0], o[1]);
    v.w = pkf16(o[2], o[3]);
    WP[q * NTHR + t] = v;
}

// G/I MFMA A-fragments (layout HW-verified: rounds 2/3/4 passed with it):
// lane l of tile: row = base + (l&15), k = 32s + ((l>>4)&3)*8 + e, e=0..7.
// Wave w owns 4 tiles ti: gate = ti>>1 (0=G,1=I), rows 32w + (ti&1)*16 + (l&15).
// WPA[((w*4 + ti)*8 + s)*64 + l]
__global__ __launch_bounds__(NTHR) void pack_wgi(
    const float* __restrict__ Wg, const float* __restrict__ Wi,
    uint4* __restrict__ WPA)
{
    const int idx = blockIdx.x * NTHR + threadIdx.x;   // 0..16383
    const int l  = idx & 63;
    const int s  = (idx >> 6) & 7;
    const int ti = (idx >> 9) & 3;
    const int w  = idx >> 11;
    const int row = w * 32 + (ti & 1) * 16 + (l & 15);
    const int k0  = s * 32 + ((l >> 4) & 3) * 8;
    const float* W = (ti >> 1) ? (Wi + row * HDIM + k0) : (Wg + row * HDIM + k0);
    uint4 v;
    v.x = pkf16(W[0], W[1]);
    v.y = pkf16(W[2], W[3]);
    v.z = pkf16(W[4], W[5]);
    v.w = pkf16(W[6], W[7]);
    WPA[idx] = v;
}

// ---- VIRTUAL-register MFMA (round-3 mechanics, which passed correctness):
// the allocator owns the AGPR assignment, so nothing can silently clobber it.
#define MFMA_I(ACC, A, B)                                                     \
    asm("v_mfma_f32_16x16x32_f16 %0, %1, %2, 0" : "=a"(ACC) : "a"(A), "v"(B))
#define MFMA_A(ACC, A, B)                                                     \
    asm("v_mfma_f32_16x16x32_f16 %0, %1, %2, %0" : "+a"(ACC) : "a"(A), "v"(B))
// Opaque, volatile identity: gives V a non-rematerializable def in the AGPR
// class. The allocator can no longer "reload it from memory later" (the
// round-2/3/4 FETCH explosion) — it must keep V resident in AGPRs.
#define PIN_A(V) asm volatile("" : "+a"(V))

__global__ void __launch_bounds__(NTHR)
__attribute__((amdgpu_waves_per_eu(2, 2)))   // 2 waves/EU -> 256 unified regs/wave
lstm_f16(
    const float* __restrict__ x,
    const float* __restrict__ Wgx, const float* __restrict__ bg_,
    const float* __restrict__ Wix, const float* __restrict__ bi_,
    const float* __restrict__ Wfx, const float* __restrict__ bf_,
    const float* __restrict__ Wox, const float* __restrict__ bo_,
    const float* __restrict__ Wph, const float* __restrict__ bp_,
    const uint4* __restrict__ WP,
    float* __restrict__ out)
{
    // h layout (f16): k<128 at byte 2k; k>=128 at byte 16+2k (16B pad at dword 64).
    __shared__ uint4 lfo[LQ * NTHR];                       // 155,648 B
    __shared__ float xs[SEQ];                              //   3,136 B
    __shared__ __align__(16) uint32_t hs[2][136];          //   1,088 B
    __shared__ __align__(16) float mpw[8][2][32];          //   2,048 B (per-wave G/I partials)
    __shared__ float hfin[HDIM];                           //   1,024 B  -> 162,944 total

    const int t  = threadIdx.x;
    const int b  = blockIdx.x;
    const int r  = t >> 1;
    const int kh = t & 1;
    const int ln = t & 63;
    const int wv = t >> 6;

    for (int i = t; i < SEQ; i += NTHR) xs[i] = x[b * SEQ + i];
    if (t < 136) hs[0][t] = 0u;

    #pragma unroll
    for (int c = 0; c < LQ; ++c) lfo[c * NTHR + t] = WP[c * NTHR + t];

    uint4 wq2[AQ2];
    #pragma unroll
    for (int i = 0; i < AQ2; ++i) wq2[i] = WP[(LQ + i) * NTHR + t];

    // G/I A-fragments -> AGPRs. Loaded once; PIN_A makes each value's def an
    // opaque volatile asm so it is loop-resident (no remat, no reload).
    const uint4* WPA = WP + FOQ * NTHR;
    half8_t afr[4][8];
    #pragma unroll
    for (int ti = 0; ti < 4; ++ti)
        #pragma unroll
        for (int s = 0; s < 8; ++s) {
            afr[ti][s] = u4h8(WPA[((wv * 4 + ti) * 8 + s) * 64 + ln]);
            PIN_A(afr[ti][s]);
        }

    const float wgx = Wgx[r], wix = Wix[r], wfx = Wfx[r], wox = Wox[r];
    const float bg = bg_[b], bi = bi_[b], bfv = bf_[b], bo = bo_[b];

    float cst = 0.f, hcur = 0.f;

    __syncthreads();

    #pragma unroll 1
    for (int ts = 0; ts < SEQ; ++ts) {
        const int cur = ts & 1;
        const char* hb = (const char*)&hs[cur][0];
        const float xt = xs[ts];

        // ---- MFMA: gates G,I, full K. B-frag s: lane l reads h[32s + (l>>4)*8..+7]
        // (byte 64s + lane-group*16, +16 past the pad for s>=4).
        const int bo4 = ((ln >> 4) & 3) * 16;
        f32x4_t acc0, acc1, acc2, acc3;
        {
            const half8_t b0 = *(const half8_t*)(hb + 0 * 64 + bo4);
            const half8_t b1 = *(const half8_t*)(hb + 1 * 64 + bo4);
            MFMA_I(acc0, afr[0][0], b0);
            MFMA_I(acc1, afr[1][0], b0);
            MFMA_I(acc2, afr[2][0], b0);
            MFMA_I(acc3, afr[3][0], b0);
            MFMA_A(acc0, afr[0][1], b1);
            MFMA_A(acc1, afr[1][1], b1);
            MFMA_A(acc2, afr[2][1], b1);
            MFMA_A(acc3, afr[3][1], b1);
            __builtin_amdgcn_sched_barrier(0);
            const half8_t b2 = *(const half8_t*)(hb + 2 * 64 + bo4);
            const half8_t b3 = *(const half8_t*)(hb + 3 * 64 + bo4);
            MFMA_A(acc0, afr[0][2], b2);
            MFMA_A(acc1, afr[1][2], b2);
            MFMA_A(acc2, afr[2][2], b2);
            MFMA_A(acc3, afr[3][2], b2);
            MFMA_A(acc0, afr[0][3], b3);
            MFMA_A(acc1, afr[1][3], b3);
            MFMA_A(acc2, afr[2][3], b3);
            MFMA_A(acc3, afr[3][3], b3);
            __builtin_amdgcn_sched_barrier(0);
            const half8_t b4 = *(const half8_t*)(hb + 16 + 4 * 64 + bo4);
            const half8_t b5 = *(const half8_t*)(hb + 16 + 5 * 64 + bo4);
            MFMA_A(acc0, afr[0][4], b4);
            MFMA_A(acc1, afr[1][4], b4);
            MFMA_A(acc2, afr[2][4], b4);
            MFMA_A(acc3, afr[3][4], b4);
            MFMA_A(acc0, afr[0][5], b5);
            MFMA_A(acc1, afr[1][5], b5);
            MFMA_A(acc2, afr[2][5], b5);
            MFMA_A(acc3, afr[3][5], b5);
            __builtin_amdgcn_sched_barrier(0);
            const half8_t b6 = *(const half8_t*)(hb + 16 + 6 * 64 + bo4);
            const half8_t b7 = *(const half8_t*)(hb + 16 + 7 * 64 + bo4);
            MFMA_A(acc0, afr[0][6], b6);
            MFMA_A(acc1, afr[1][6], b6);
            MFMA_A(acc2, afr[2][6], b6);
            MFMA_A(acc3, afr[3][6], b6);
            MFMA_A(acc0, afr[0][7], b7);
            MFMA_A(acc1, afr[1][7], b7);
            MFMA_A(acc2, afr[2][7], b7);
            MFMA_A(acc3, afr[3][7], b7);
        }
        __builtin_amdgcn_sched_barrier(0);

        // ---- VALU: gates F,O, this thread's K-half (128 k = 32 quads) ----
        // Also provides the MFMA -> acc-read hazard distance (~128 VALU ops).
        float af = 0.f, ao = 0.f;
        const char* hv = hb + (kh ? 272 : 0);
        #pragma unroll
        for (int c = 0; c < 16; ++c) {
            const uint4 hh = *(const uint4*)(hv + 16 * c);
            const int q0 = 2 * c, q1 = 2 * c + 1;
            uint4 w0, w1;
            if (q0 < LQ) w0 = lfo[q0 * NTHR + t]; else w0 = wq2[q0 - LQ];
            if (q1 < LQ) w1 = lfo[q1 * NTHR + t]; else w1 = wq2[q1 - LQ];
            af = dot2(hh.x, w0.x, af);
            af = dot2(hh.y, w0.y, af);
            ao = dot2(hh.x, w0.z, ao);
            ao = dot2(hh.y, w0.w, ao);
            af = dot2(hh.z, w1.x, af);
            af = dot2(hh.w, w1.y, af);
            ao = dot2(hh.z, w1.z, ao);
            ao = dot2(hh.w, w1.w, ao);
            if ((c & 3) == 3) __builtin_amdgcn_sched_barrier(0);
        }

        // ---- intra-wave handoff of G,I partials (no barrier needed) ----
        // D layout: col = ln&15, row-in-tile = (ln>>4)*4 + j; broadcast-B makes
        // all cols equal. Col-0 lanes {0,16,32,48} write their 4 rows per tile.
        if ((ln & 15) == 0) {
            const int lg = ln >> 4;
            f32x4_t t0 = acc0;                     // v_accvgpr_read x4
            *(f32x4_t*)&mpw[wv][0][0 * 16 + lg * 4] = t0;
            f32x4_t t1 = acc1;
            *(f32x4_t*)&mpw[wv][0][1 * 16 + lg * 4] = t1;
            f32x4_t t2 = acc2;
            *(f32x4_t*)&mpw[wv][1][0 * 16 + lg * 4] = t2;
            f32x4_t t3 = acc3;
            *(f32x4_t*)&mpw[wv][1][1 * 16 + lg * 4] = t3;
        }
        asm volatile("s_waitcnt lgkmcnt(0)" ::: "memory");
        __builtin_amdgcn_sched_barrier(0);

        const int r5 = r & 31;
        float sg = mpw[wv][0][r5] + fmaf(wgx, xt, bg);
        float si = mpw[wv][1][r5] + fmaf(wix, xt, bi);
        af += __shfl_xor(af, 1);
        ao += __shfl_xor(ao, 1);
        const float sf = af + fmaf(wfx, xt, bfv);
        const float so = ao + fmaf(wox, xt, bo);

        const float g  = tanh_f(sg);
        const float iv = sigmoid_f(si);
        const float fv = sigmoid_f(sf);
        const float ov = sigmoid_f(so);
        cst  = fmaf(g, iv, cst * fv);
        hcur = tanh_f(cst) * ov;

        // padded write: byte 2r (+16 for r>=128) -> half-index r + (r>>7)*8
        if (kh == 0) ((_Float16*)&hs[cur ^ 1][0])[r + ((r >> 7) << 3)] = (_Float16)hcur;

        __syncthreads();   // h(ts) visible to all waves
    }

    if (kh == 0) hfin[r] = hcur;
    __syncthreads();

    if (t < NCLS) {
        float acc = bp_[b];
        #pragma unroll 4
        for (int k = 0; k < HDIM; ++k) acc = fmaf(Wph[t * HDIM + k], hfin[k], acc);
        out[b * NCLS + t] = acc;
    }
}

// Fallback (no workspace): fp32 weights streamed from L2. Correctness insurance only.
__global__ __launch_bounds__(HDIM) void lstm_fb(
    const float* __restrict__ x,
    const float* __restrict__ Wgx, const float* __restrict__ Wgh, const float* __restrict__ bg_,
    const float* __restrict__ Wix, const float* __restrict__ Wih, const float* __restrict__ bi_,
    const float* __restrict__ Wfx, const float* __restrict__ Wfh, const float* __restrict__ bf_,
    const float* __restrict__ Wox, const float* __restrict__ Woh, const float* __restrict__ bo_,
    const float* __restrict__ Wph, const float* __restrict__ bp_,
    float* __restrict__ out)
{
    __shared__ float xs[SEQ];
    __shared__ float hsv[HDIM];
    const int r = threadIdx.x, b = blockIdx.x;
    for (int i = r; i < SEQ; i += HDIM) xs[i] = x[b * SEQ + i];
    hsv[r] = 0.f;
    float c = 0.f;
    const float wgx = Wgx[r], wix = Wix[r], wfx = Wfx[r], wox = Wox[r];
    const float bg = bg_[b], bi = bi_[b], bfv = bf_[b], bo = bo_[b];
    __syncthreads();
    for (int ts = 0; ts < SEQ; ++ts) {
        const float xt = xs[ts];
        float ag = fmaf(wgx, xt, bg);
        float ai = fmaf(wix, xt, bi);
        float af = fmaf(wfx, xt, bfv);
        float ao = fmaf(wox, xt, bo);
        #pragma unroll 4
        for (int k = 0; k < HDIM; ++k) {
            const float hv = hsv[k];
            ag = fmaf(Wgh[r * HDIM + k], hv, ag);
            ai = fmaf(Wih[r * HDIM + k], hv, ai);
            af = fmaf(Wfh[r * HDIM + k], hv, af);
            ao = fmaf(Woh[r * HDIM + k], hv, ao);
        }
        const float g  = tanhf(ag);
        const float iv = 1.f / (1.f + expf(-ai));
        const float fv = 1.f / (1.f + expf(-af));
        const float ov = 1.f / (1.f + expf(-ao));
        c = fmaf(g, iv, c * fv);
        const float hn = tanhf(c) * ov;
        __syncthreads();
        hsv[r] = hn;
        __syncthreads();
    }
    if (r < NCLS) {
        float acc = bp_[b];
        for (int k = 0; k < HDIM; ++k) acc = fmaf(Wph[r * HDIM + k], hsv[k], acc);
        out[b * NCLS + r] = acc;
    }
}

extern "C" void kernel_launch(void* const* d_in, const int* in_sizes, int n_in,
                              void* d_out, int out_size, void* d_ws, size_t ws_size,
                              hipStream_t stream) {
    const float* x   = (const float*)d_in[0];
    const float* Wgx = (const float*)d_in[1];
    const float* Wgh = (const float*)d_in[2];
    const float* bg  = (const float*)d_in[3];
    const float* Wix = (const float*)d_in[4];
    const float* Wih = (const float*)d_in[5];
    const float* bi  = (const float*)d_in[6];
    const float* Wfx = (const float*)d_in[7];
    const float* Wfh = (const float*)d_in[8];
    const float* bf  = (const float*)d_in[9];
    const float* Wox = (const float*)d_in[10];
    const float* Woh = (const float*)d_in[11];
    const float* bo  = (const float*)d_in[12];
    const float* Wph = (const float*)d_in[13];
    const float* bp  = (const float*)d_in[14];
    float* out = (float*)d_out;

    // WP: 32*512 F/O quads (256 KB) + 8*4*8*64 G/I fragment quads (256 KB) = 512 KB
    const size_t need = (size_t)(FOQ * NTHR + 8 * 4 * 8 * 64) * sizeof(uint4);
    if (ws_size >= need) {
        uint4* WP = (uint4*)d_ws;
        pack_wfo<<<dim3(FOQ), dim3(NTHR), 0, stream>>>(Wfh, Woh, WP);
        pack_wgi<<<dim3(32), dim3(NTHR), 0, stream>>>(Wgh, Wih, WP + FOQ * NTHR);
        lstm_f16<<<dim3(NB), dim3(NTHR), 0, stream>>>(
            x, Wgx, bg, Wix, bi, Wfx, bf, Wox, bo, Wph, bp, (const uint4*)WP, out);
    } else {
        lstm_fb<<<dim3(NB), dim3(HDIM), 0, stream>>>(
            x, Wgx, Wgh, bg, Wix, Wih, bi, Wfx, Wfh, bf, Wox, Woh, bo, Wph, bp, out);
    }
}

// Round 8
// 8963.789 us; speedup vs baseline: 1.2075x; 1.2075x over previous
//
#include <hip/hip_runtime.h>
#include <stdint.h>

#define HDIM 256
#define SEQ  784
#define NB   256
#define NCLS 10
#define NTHR 512
#define LQ   19              // F/O weight quads per thread in LDS (155,648 B)
#define AQ2  13              // F/O weight quads per thread in arch VGPRs (52 regs)
#define FOQ  32              // total F/O quads per thread (128 k-cols x 2 gates)

typedef _Float16 half2_t __attribute__((ext_vector_type(2)));
typedef _Float16 half8_t __attribute__((ext_vector_type(8)));
typedef float    f32x4_t __attribute__((ext_vector_type(4)));

__device__ __forceinline__ half2_t u2h(uint32_t u) {
    union { uint32_t u; half2_t h; } v; v.u = u; return v.h;
}
__device__ __forceinline__ uint32_t pkf16(float a, float b) {
    union { half2_t h; uint32_t u; } v;
    v.h.x = (_Float16)a; v.h.y = (_Float16)b; return v.u;
}
__device__ __forceinline__ half8_t u4h8(uint4 u) {
    union { uint4 u; half8_t h; } v; v.u = u; return v.h;
}

#if __has_builtin(__builtin_amdgcn_fdot2)
__device__ __forceinline__ float dot2(uint32_t h, uint32_t w, float acc) {
    return __builtin_amdgcn_fdot2(u2h(h), u2h(w), acc, false);
}
#else
__device__ __forceinline__ float dot2(uint32_t h, uint32_t w, float acc) {
    half2_t hv = u2h(h), wv = u2h(w);
    acc = fmaf((float)hv.x, (float)wv.x, acc);
    return fmaf((float)hv.y, (float)wv.y, acc);
}
#endif

#if __has_builtin(__builtin_amdgcn_rcpf)
__device__ __forceinline__ float fast_rcp(float x) { return __builtin_amdgcn_rcpf(x); }
#else
__device__ __forceinline__ float fast_rcp(float x) { return 1.f / x; }
#endif

__device__ __forceinline__ float sigmoid_f(float x) {
    return fast_rcp(1.f + __expf(-x));
}
__device__ __forceinline__ float tanh_f(float x) {
    return fmaf(2.f, fast_rcp(1.f + __expf(-2.f * x)), -1.f);
}

// F/O weights: WP[q*NTHR + t], t=(r<<1)|kh, quad q covers k0 = kh*128 + 4q:
// {F(k0,k0+1), F(k0+2,k0+3), O(k0,k0+1), O(k0+2,k0+3)} as f16 pairs.
__global__ __launch_bounds__(NTHR) void pack_wfo(
    const float* __restrict__ Wf, const float* __restrict__ Wo,
    uint4* __restrict__ WP)
{
    const int q = blockIdx.x;          // 0..31
    const int t = threadIdx.x;         // 0..511
    const int r = t >> 1, kh = t & 1;
    const int k0 = kh * 128 + 4 * q;
    const float* f = Wf + r * HDIM + k0;
    const float* o = Wo + r * HDIM + k0;
    uint4 v;
    v.x = pkf16(f[0], f[1]);
    v.y = pkf16(f[2], f[3]);
    v.z = pkf16(o[0], o[1]);
    v.w = pkf16(o[2], o[3]);
    WP[q * NTHR + t] = v;
}

// G/I MFMA A-fragments (layout HW-verified: rounds 2/3/4/7 passed with it):
// lane l of tile: row = base + (l&15), k = 32s + ((l>>4)&3)*8 + e, e=0..7.
// Wave w owns 4 tiles ti: gate = ti>>1 (0=G,1=I), rows 32w + (ti&1)*16 + (l&15).
// WPA[((w*4 + ti)*8 + s)*64 + l]
__global__ __launch_bounds__(NTHR) void pack_wgi(
    const float* __restrict__ Wg, const float* __restrict__ Wi,
    uint4* __restrict__ WPA)
{
    const int idx = blockIdx.x * NTHR + threadIdx.x;   // 0..16383
    const int l  = idx & 63;
    const int s  = (idx >> 6) & 7;
    const int ti = (idx >> 9) & 3;
    const int w  = idx >> 11;
    const int row = w * 32 + (ti & 1) * 16 + (l & 15);
    const int k0  = s * 32 + ((l >> 4) & 3) * 8;
    const float* W = (ti >> 1) ? (Wi + row * HDIM + k0) : (Wg + row * HDIM + k0);
    uint4 v;
    v.x = pkf16(W[0], W[1]);
    v.y = pkf16(W[2], W[3]);
    v.z = pkf16(W[4], W[5]);
    v.w = pkf16(W[6], W[7]);
    WPA[idx] = v;
}

// ---- Budget-exact register plan (the one untried cell):
//   AGPR class: afr ONLY = 32 quads = 128 regs -> class completely full, the
//     allocator cannot spill anything else INTO it, and PIN_A (volatile def)
//     forbids remat/reload of the weights themselves.
//   Arch class: accumulators "v" (16) + wq2 (52) + fenced b-frags (8) + temps
//     ~= 113 <= 128 -> no scratch spill.
// Mixed-operand MFMA (D/C=VGPR, A=AGPR, B=VGPR) is legal on gfx950 (ISA §10).
#define MFMA_I(ACC, A, B)                                                     \
    asm("v_mfma_f32_16x16x32_f16 %0, %1, %2, 0" : "=v"(ACC) : "a"(A), "v"(B))
#define MFMA_A(ACC, A, B)                                                     \
    asm("v_mfma_f32_16x16x32_f16 %0, %1, %2, %0" : "+v"(ACC) : "a"(A), "v"(B))
#define PIN_A(V) asm volatile("" : "+a"(V))

__global__ void __launch_bounds__(NTHR)
__attribute__((amdgpu_waves_per_eu(2, 2)))   // 2 waves/EU -> 256 unified regs/wave
lstm_f16(
    const float* __restrict__ x,
    const float* __restrict__ Wgx, const float* __restrict__ bg_,
    const float* __restrict__ Wix, const float* __restrict__ bi_,
    const float* __restrict__ Wfx, const float* __restrict__ bf_,
    const float* __restrict__ Wox, const float* __restrict__ bo_,
    const float* __restrict__ Wph, const float* __restrict__ bp_,
    const uint4* __restrict__ WP,
    float* __restrict__ out)
{
    // h layout (f16): k<128 at byte 2k; k>=128 at byte 16+2k (16B pad at dword 64).
    __shared__ uint4 lfo[LQ * NTHR];                       // 155,648 B
    __shared__ float xs[SEQ];                              //   3,136 B
    __shared__ __align__(16) uint32_t hs[2][136];          //   1,088 B
    __shared__ __align__(16) float mpw[8][2][32];          //   2,048 B (per-wave G/I partials)
    __shared__ float hfin[HDIM];                           //   1,024 B  -> 162,944 total

    const int t  = threadIdx.x;
    const int b  = blockIdx.x;
    const int r  = t >> 1;
    const int kh = t & 1;
    const int ln = t & 63;
    const int wv = t >> 6;

    for (int i = t; i < SEQ; i += NTHR) xs[i] = x[b * SEQ + i];
    if (t < 136) hs[0][t] = 0u;

    #pragma unroll
    for (int c = 0; c < LQ; ++c) lfo[c * NTHR + t] = WP[c * NTHR + t];

    uint4 wq2[AQ2];
    #pragma unroll
    for (int i = 0; i < AQ2; ++i) wq2[i] = WP[(LQ + i) * NTHR + t];

    // G/I A-fragments -> virtual AGPRs (exactly fills the 128-reg class).
    const uint4* WPA = WP + FOQ * NTHR;
    half8_t afr[4][8];
    #pragma unroll
    for (int ti = 0; ti < 4; ++ti)
        #pragma unroll
        for (int s = 0; s < 8; ++s) {
            afr[ti][s] = u4h8(WPA[((wv * 4 + ti) * 8 + s) * 64 + ln]);
            PIN_A(afr[ti][s]);
        }

    const float wgx = Wgx[r], wix = Wix[r], wfx = Wfx[r], wox = Wox[r];
    const float bg = bg_[b], bi = bi_[b], bfv = bf_[b], bo = bo_[b];

    float cst = 0.f, hcur = 0.f;

    __syncthreads();

    #pragma unroll 1
    for (int ts = 0; ts < SEQ; ++ts) {
        const int cur = ts & 1;
        const char* hb = (const char*)&hs[cur][0];
        const float xt = xs[ts];

        // ---- MFMA: gates G,I, full K. B-frag s: lane l reads h[32s + (l>>4)*8..+7]
        // (byte 64s + lane-group*16, +16 past the pad for s>=4).
        const int bo4 = ((ln >> 4) & 3) * 16;
        f32x4_t acc0, acc1, acc2, acc3;
        {
            const half8_t b0 = *(const half8_t*)(hb + 0 * 64 + bo4);
            const half8_t b1 = *(const half8_t*)(hb + 1 * 64 + bo4);
            MFMA_I(acc0, afr[0][0], b0);
            MFMA_I(acc1, afr[1][0], b0);
            MFMA_I(acc2, afr[2][0], b0);
            MFMA_I(acc3, afr[3][0], b0);
            MFMA_A(acc0, afr[0][1], b1);
            MFMA_A(acc1, afr[1][1], b1);
            MFMA_A(acc2, afr[2][1], b1);
            MFMA_A(acc3, afr[3][1], b1);
            __builtin_amdgcn_sched_barrier(0);
            const half8_t b2 = *(const half8_t*)(hb + 2 * 64 + bo4);
            const half8_t b3 = *(const half8_t*)(hb + 3 * 64 + bo4);
            MFMA_A(acc0, afr[0][2], b2);
            MFMA_A(acc1, afr[1][2], b2);
            MFMA_A(acc2, afr[2][2], b2);
            MFMA_A(acc3, afr[3][2], b2);
            MFMA_A(acc0, afr[0][3], b3);
            MFMA_A(acc1, afr[1][3], b3);
            MFMA_A(acc2, afr[2][3], b3);
            MFMA_A(acc3, afr[3][3], b3);
            __builtin_amdgcn_sched_barrier(0);
            const half8_t b4 = *(const half8_t*)(hb + 16 + 4 * 64 + bo4);
            const half8_t b5 = *(const half8_t*)(hb + 16 + 5 * 64 + bo4);
            MFMA_A(acc0, afr[0][4], b4);
            MFMA_A(acc1, afr[1][4], b4);
            MFMA_A(acc2, afr[2][4], b4);
            MFMA_A(acc3, afr[3][4], b4);
            MFMA_A(acc0, afr[0][5], b5);
            MFMA_A(acc1, afr[1][5], b5);
            MFMA_A(acc2, afr[2][5], b5);
            MFMA_A(acc3, afr[3][5], b5);
            __builtin_amdgcn_sched_barrier(0);
            const half8_t b6 = *(const half8_t*)(hb + 16 + 6 * 64 + bo4);
            const half8_t b7 = *(const half8_t*)(hb + 16 + 7 * 64 + bo4);
            MFMA_A(acc0, afr[0][6], b6);
            MFMA_A(acc1, afr[1][6], b6);
            MFMA_A(acc2, afr[2][6], b6);
            MFMA_A(acc3, afr[3][6], b6);
            MFMA_A(acc0, afr[0][7], b7);
            MFMA_A(acc1, afr[1][7], b7);
            MFMA_A(acc2, afr[2][7], b7);
            MFMA_A(acc3, afr[3][7], b7);
        }
        __builtin_amdgcn_sched_barrier(0);

        // ---- VALU: gates F,O, this thread's K-half (128 k = 32 quads) ----
        // Also provides the MFMA -> acc-read hazard distance (~128 VALU ops).
        float af = 0.f, ao = 0.f;
        const char* hv = hb + (kh ? 272 : 0);
        #pragma unroll
        for (int c = 0; c < 16; ++c) {
            const uint4 hh = *(const uint4*)(hv + 16 * c);
            const int q0 = 2 * c, q1 = 2 * c + 1;
            uint4 w0, w1;
            if (q0 < LQ) w0 = lfo[q0 * NTHR + t]; else w0 = wq2[q0 - LQ];
            if (q1 < LQ) w1 = lfo[q1 * NTHR + t]; else w1 = wq2[q1 - LQ];
            af = dot2(hh.x, w0.x, af);
            af = dot2(hh.y, w0.y, af);
            ao = dot2(hh.x, w0.z, ao);
            ao = dot2(hh.y, w0.w, ao);
            af = dot2(hh.z, w1.x, af);
            af = dot2(hh.w, w1.y, af);
            ao = dot2(hh.z, w1.z, ao);
            ao = dot2(hh.w, w1.w, ao);
            if ((c & 3) == 3) __builtin_amdgcn_sched_barrier(0);
        }

        // ---- intra-wave handoff of G,I partials (no barrier needed) ----
        // D layout: col = ln&15, row-in-tile = (ln>>4)*4 + j; broadcast-B makes
        // all cols equal. Col-0 lanes {0,16,32,48} write their 4 rows per tile.
        if ((ln & 15) == 0) {
            const int lg = ln >> 4;
            *(f32x4_t*)&mpw[wv][0][0 * 16 + lg * 4] = acc0;
            *(f32x4_t*)&mpw[wv][0][1 * 16 + lg * 4] = acc1;
            *(f32x4_t*)&mpw[wv][1][0 * 16 + lg * 4] = acc2;
            *(f32x4_t*)&mpw[wv][1][1 * 16 + lg * 4] = acc3;
        }
        asm volatile("s_waitcnt lgkmcnt(0)" ::: "memory");
        __builtin_amdgcn_sched_barrier(0);

        const int r5 = r & 31;
        float sg = mpw[wv][0][r5] + fmaf(wgx, xt, bg);
        float si = mpw[wv][1][r5] + fmaf(wix, xt, bi);
        af += __shfl_xor(af, 1);
        ao += __shfl_xor(ao, 1);
        const float sf = af + fmaf(wfx, xt, bfv);
        const float so = ao + fmaf(wox, xt, bo);

        const float g  = tanh_f(sg);
        const float iv = sigmoid_f(si);
        const float fv = sigmoid_f(sf);
        const float ov = sigmoid_f(so);
        cst  = fmaf(g, iv, cst * fv);
        hcur = tanh_f(cst) * ov;

        // padded write: byte 2r (+16 for r>=128) -> half-index r + (r>>7)*8
        if (kh == 0) ((_Float16*)&hs[cur ^ 1][0])[r + ((r >> 7) << 3)] = (_Float16)hcur;

        __syncthreads();   // h(ts) visible to all waves
    }

    if (kh == 0) hfin[r] = hcur;
    __syncthreads();

    if (t < NCLS) {
        float acc = bp_[b];
        #pragma unroll 4
        for (int k = 0; k < HDIM; ++k) acc = fmaf(Wph[t * HDIM + k], hfin[k], acc);
        out[b * NCLS + t] = acc;
    }
}

// Fallback (no workspace): fp32 weights streamed from L2. Correctness insurance only.
__global__ __launch_bounds__(HDIM) void lstm_fb(
    const float* __restrict__ x,
    const float* __restrict__ Wgx, const float* __restrict__ Wgh, const float* __restrict__ bg_,
    const float* __restrict__ Wix, const float* __restrict__ Wih, const float* __restrict__ bi_,
    const float* __restrict__ Wfx, const float* __restrict__ Wfh, const float* __restrict__ bf_,
    const float* __restrict__ Wox, const float* __restrict__ Woh, const float* __restrict__ bo_,
    const float* __restrict__ Wph, const float* __restrict__ bp_,
    float* __restrict__ out)
{
    __shared__ float xs[SEQ];
    __shared__ float hsv[HDIM];
    const int r = threadIdx.x, b = blockIdx.x;
    for (int i = r; i < SEQ; i += HDIM) xs[i] = x[b * SEQ + i];
    hsv[r] = 0.f;
    float c = 0.f;
    const float wgx = Wgx[r], wix = Wix[r], wfx = Wfx[r], wox = Wox[r];
    const float bg = bg_[b], bi = bi_[b], bfv = bf_[b], bo = bo_[b];
    __syncthreads();
    for (int ts = 0; ts < SEQ; ++ts) {
        const float xt = xs[ts];
        float ag = fmaf(wgx, xt, bg);
        float ai = fmaf(wix, xt, bi);
        float af = fmaf(wfx, xt, bfv);
        float ao = fmaf(wox, xt, bo);
        #pragma unroll 4
        for (int k = 0; k < HDIM; ++k) {
            const float hv = hsv[k];
            ag = fmaf(Wgh[r * HDIM + k], hv, ag);
            ai = fmaf(Wih[r * HDIM + k], hv, ai);
            af = fmaf(Wfh[r * HDIM + k], hv, af);
            ao = fmaf(Woh[r * HDIM + k], hv, ao);
        }
        const float g  = tanhf(ag);
        const float iv = 1.f / (1.f + expf(-ai));
        const float fv = 1.f / (1.f + expf(-af));
        const float ov = 1.f / (1.f + expf(-ao));
        c = fmaf(g, iv, c * fv);
        const float hn = tanhf(c) * ov;
        __syncthreads();
        hsv[r] = hn;
        __syncthreads();
    }
    if (r < NCLS) {
        float acc = bp_[b];
        for (int k = 0; k < HDIM; ++k) acc = fmaf(Wph[r * HDIM + k], hsv[k], acc);
        out[b * NCLS + r] = acc;
    }
}

extern "C" void kernel_launch(void* const* d_in, const int* in_sizes, int n_in,
                              void* d_out, int out_size, void* d_ws, size_t ws_size,
                              hipStream_t stream) {
    const float* x   = (const float*)d_in[0];
    const float* Wgx = (const float*)d_in[1];
    const float* Wgh = (const float*)d_in[2];
    const float* bg  = (const float*)d_in[3];
    const float* Wix = (const float*)d_in[4];
    const float* Wih = (const float*)d_in[5];
    const float* bi  = (const float*)d_in[6];
    const float* Wfx = (const float*)d_in[7];
    const float* Wfh = (const float*)d_in[8];
    const float* bf  = (const float*)d_in[9];
    const float* Wox = (const float*)d_in[10];
    const float* Woh = (const float*)d_in[11];
    const float* bo  = (const float*)d_in[12];
    const float* Wph = (const float*)d_in[13];
    const float* bp  = (const float*)d_in[14];
    float* out = (float*)d_out;

    // WP: 32*512 F/O quads (256 KB) + 8*4*8*64 G/I fragment quads (256 KB) = 512 KB
    const size_t need = (size_t)(FOQ * NTHR + 8 * 4 * 8 * 64) * sizeof(uint4);
    if (ws_size >= need) {
        uint4* WP = (uint4*)d_ws;
        pack_wfo<<<dim3(FOQ), dim3(NTHR), 0, stream>>>(Wfh, Woh, WP);
        pack_wgi<<<dim3(32), dim3(NTHR), 0, stream>>>(Wgh, Wih, WP + FOQ * NTHR);
        lstm_f16<<<dim3(NB), dim3(NTHR), 0, stream>>>(
            x, Wgx, bg, Wix, bi, Wfx, bf, Wox, bo, Wph, bp, (const uint4*)WP, out);
    } else {
        lstm_fb<<<dim3(NB), dim3(HDIM), 0, stream>>>(
            x, Wgx, Wgh, bg, Wix, Wih, bi, Wfx, Wfh, bf, Wox, Woh, bo, Wph, bp, out);
    }
}